// Round 1
// baseline (124.469 us; speedup 1.0000x reference)
//
#include <hip/hip_runtime.h>
#include <hip/hip_bf16.h>

typedef __attribute__((ext_vector_type(8))) short short8;   // 8 bf16 (4 VGPRs)
typedef __attribute__((ext_vector_type(4))) float float4v;  // 4 fp32 acc

#define C2EXP 2.8853900817779268f  /* 2*log2(e): exp(2s) = exp2(C2EXP*s), tau=0.5 */
#define JB_PER_BLOCK 4

__device__ __forceinline__ float bf16lo(unsigned int u){ return __uint_as_float((u & 0xFFFFu) << 16); }
__device__ __forceinline__ float bf16hi(unsigned int u){ return __uint_as_float(u & 0xFFFF0000u); }

// K1: row-normalize fp32 features (norm clamp @1e-8, like reference), cast to bf16,
// pack 2/lane into uint. Also zero the t accumulator (ws is poisoned every launch).
__global__ void k_normalize(const float* __restrict__ f, unsigned int* __restrict__ zb,
                            float* __restrict__ t, int N){
    int lane = threadIdx.x & 63;
    int row  = blockIdx.x * 4 + (threadIdx.x >> 6);
    int gid  = blockIdx.x * 256 + threadIdx.x;
    if (gid < N) t[gid] = 0.0f;
    if (row >= N) return;
    const float2* fr = (const float2*)(f + (size_t)row * 128);
    float2 v = fr[lane];
    float ss = v.x * v.x + v.y * v.y;
    #pragma unroll
    for (int m = 1; m < 64; m <<= 1) ss += __shfl_xor(ss, m);
    float scale = 1.0f / fmaxf(sqrtf(ss), 1e-8f);
    __hip_bfloat16 h0 = __float2bfloat16(v.x * scale);
    __hip_bfloat16 h1 = __float2bfloat16(v.y * scale);
    unsigned short b0, b1;
    __builtin_memcpy(&b0, &h0, 2);
    __builtin_memcpy(&b1, &h1, 2);
    zb[row * 64 + lane] = (unsigned int)b0 | ((unsigned int)b1 << 16);
}

// K2: per-group (one wave per group): pos[i] = sum_{j in group, j!=i} exp(2*cos),
// self[i] = exp(2*z_i.z_i). Group start derived from num_crops (general, no hard-code).
__global__ void k_pos(const unsigned int* __restrict__ zb, const int* __restrict__ nc,
                      float* __restrict__ possum, float* __restrict__ selfs, int G){
    int g = blockIdx.x, lane = threadIdx.x;
    int st = 0;
    for (int i = lane; i < g; i += 64) st += nc[i];
    #pragma unroll
    for (int m = 1; m < 64; m <<= 1) st += __shfl_xor(st, m);
    int c = nc[g];
    for (int a = 0; a < c; a++){
        unsigned int ua = zb[(st + a) * 64 + lane];
        float a0 = bf16lo(ua), a1 = bf16hi(ua);
        float pacc = 0.0f;
        for (int b = 0; b < c; b++){
            unsigned int ub = zb[(st + b) * 64 + lane];
            float s = a0 * bf16lo(ub) + a1 * bf16hi(ub);
            #pragma unroll
            for (int m = 1; m < 64; m <<= 1) s += __shfl_xor(s, m);
            float e = exp2f(C2EXP * s);
            if (b == a){ if (lane == 0) selfs[st + a] = e; }
            else pacc += e;
        }
        if (lane == 0) possum[st + a] = pacc;
    }
}

// K3: tiled S = Z Z^T with bf16 MFMA; per element e = exp(2s); accumulate full row
// sums t[i] (no masks). 128x128 tile per block; block covers JB_PER_BLOCK j-tiles.
// A-tile persistent full K=128 in LDS (stride 136 elems: 16B-mult, 2-way bank alias).
// B-tile staged in K-chunks of 64 (stride 72 elems).
__global__ __launch_bounds__(256) void k_gram(const unsigned int* __restrict__ zb,
                                              float* __restrict__ t, int N){
    __shared__ unsigned short Asm[128 * 136];
    __shared__ unsigned short Bsm[128 * 72];
    const uint4* zv = (const uint4*)zb;  // one uint4 = 8 bf16; row stride = 16 uint4
    int tid  = threadIdx.x;
    int lane = tid & 63, w = tid >> 6;
    int wm = w >> 1, wn = w & 1;          // 2x2 wave grid of 64x64 quadrants
    int quad = lane >> 4, l15 = lane & 15;
    int ib = blockIdx.x, jc = blockIdx.y;

    // Stage A tile (rows ib*128..+127, full K=128): 2048 uint4 / 256 threads
    #pragma unroll
    for (int it = 0; it < 8; it++){
        int v = tid + it * 256;
        int row = v >> 4, kv = v & 15;
        uint4 d = zv[(size_t)(ib * 128 + row) * 16 + kv];
        *((uint4*)&Asm[row * 136 + kv * 8]) = d;
    }

    float ts[4][4];
    #pragma unroll
    for (int mi = 0; mi < 4; mi++)
        #pragma unroll
        for (int r = 0; r < 4; r++) ts[mi][r] = 0.0f;

    for (int jb = 0; jb < JB_PER_BLOCK; jb++){
        int j0 = (jc * JB_PER_BLOCK + jb) * 128;
        float4v acc[4][4];
        #pragma unroll
        for (int mi = 0; mi < 4; mi++)
            #pragma unroll
            for (int ni = 0; ni < 4; ni++)
                acc[mi][ni] = (float4v){0.0f, 0.0f, 0.0f, 0.0f};

        #pragma unroll
        for (int kc = 0; kc < 2; kc++){
            __syncthreads();  // protect Bsm readers from previous chunk / A staging for jb==0
            #pragma unroll
            for (int it = 0; it < 4; it++){
                int v = tid + it * 256;
                int row = v >> 3, kv = v & 7;
                uint4 d = zv[(size_t)(j0 + row) * 16 + kc * 8 + kv];
                *((uint4*)&Bsm[row * 72 + kv * 8]) = d;
            }
            __syncthreads();
            #pragma unroll
            for (int kk = 0; kk < 2; kk++){
                int ki = kc * 2 + kk;   // global k-step (k = ki*32)
                short8 af[4], bfr[4];
                #pragma unroll
                for (int mi = 0; mi < 4; mi++){
                    int r = wm * 64 + mi * 16 + l15;
                    af[mi] = *(const short8*)&Asm[r * 136 + ki * 32 + quad * 8];
                }
                #pragma unroll
                for (int ni = 0; ni < 4; ni++){
                    int r = wn * 64 + ni * 16 + l15;
                    bfr[ni] = *(const short8*)&Bsm[r * 72 + kk * 32 + quad * 8];
                }
                #pragma unroll
                for (int mi = 0; mi < 4; mi++)
                    #pragma unroll
                    for (int ni = 0; ni < 4; ni++)
                        acc[mi][ni] = __builtin_amdgcn_mfma_f32_16x16x32_bf16(
                            af[mi], bfr[ni], acc[mi][ni], 0, 0, 0);
            }
        }
        // Epilogue: e = exp(2s), accumulate row partial sums (C layout: col=lane&15,
        // row_local = wm*64 + mi*16 + quad*4 + r)
        #pragma unroll
        for (int mi = 0; mi < 4; mi++)
            #pragma unroll
            for (int ni = 0; ni < 4; ni++)
                #pragma unroll
                for (int r = 0; r < 4; r++)
                    ts[mi][r] += exp2f(C2EXP * acc[mi][ni][r]);
    }

    // Reduce across the 16 column-lanes (same quad), then one atomic per row per wave
    #pragma unroll
    for (int mi = 0; mi < 4; mi++)
        #pragma unroll
        for (int r = 0; r < 4; r++){
            float v = ts[mi][r];
            v += __shfl_xor(v, 1);
            v += __shfl_xor(v, 2);
            v += __shfl_xor(v, 4);
            v += __shfl_xor(v, 8);
            ts[mi][r] = v;
        }
    if (l15 == 0){
        #pragma unroll
        for (int mi = 0; mi < 4; mi++)
            #pragma unroll
            for (int r = 0; r < 4; r++){
                int i = ib * 128 + wm * 64 + mi * 16 + quad * 4 + r;
                atomicAdd(&t[i], ts[mi][r]);
            }
    }
}

// K4: loss = mean over rows of log(neg) - log(pos); neg = t - pos - self
__global__ void k_final(const float* __restrict__ t, const float* __restrict__ possum,
                        const float* __restrict__ selfs, float* __restrict__ out, int N){
    int tid = threadIdx.x;
    float s = 0.0f;
    for (int r = tid; r < N; r += 256){
        float p = possum[r];
        float n = t[r] - p - selfs[r];
        s += logf(n) - logf(p);
    }
    #pragma unroll
    for (int m = 1; m < 64; m <<= 1) s += __shfl_xor(s, m);
    __shared__ float red[4];
    if ((tid & 63) == 0) red[tid >> 6] = s;
    __syncthreads();
    if (tid == 0) out[0] = (red[0] + red[1] + red[2] + red[3]) / (float)N;
}

extern "C" void kernel_launch(void* const* d_in, const int* in_sizes, int n_in,
                              void* d_out, int out_size, void* d_ws, size_t ws_size,
                              hipStream_t stream){
    const float* f  = (const float*)d_in[0];
    const int*   nc = (const int*)d_in[1];
    int N = in_sizes[0] / 128;   // 8192
    int G = in_sizes[1];         // 2048

    unsigned int* zb = (unsigned int*)d_ws;                       // N*256 bytes bf16 z
    float* t     = (float*)((char*)d_ws + (size_t)N * 256);       // N fp32
    float* pos   = t + N;
    float* selfs = pos + N;
    float* out   = (float*)d_out;

    k_normalize<<<N / 4, 256, 0, stream>>>(f, zb, t, N);
    k_pos<<<G, 64, 0, stream>>>(zb, nc, pos, selfs, G);
    dim3 grid(N / 128, N / (128 * JB_PER_BLOCK));
    k_gram<<<grid, 256, 0, stream>>>(zb, t, N);
    k_final<<<1, 256, 0, stream>>>(t, pos, selfs, out, N);
}